// Round 15
// baseline (256.415 us; speedup 1.0000x reference)
//
#include <hip/hip_runtime.h>
#include <hip/hip_bf16.h>

#define EPSV 1e-5f

// workspace layout: [wB2][xTp][stats]
#define WB2_ELEMS (2*4*36*256*32)          // [p][nt(4)][kt(36)][nl(256)][kk(32)] bf16
#define WB2_BYTES ((size_t)WB2_ELEMS*2)    // 4,718,592
#define XTP_ELEMS (8*68*68*128)            // padded channels-last x, bf16
#define XTP_BYTES ((size_t)XTP_ELEMS*2)    // 9,469,952
#define STATS_OFF (WB2_BYTES + XTP_BYTES)  // 1024 float2 partials

// k_conv dynamic LDS: 3 bufs x (A 16 KB + B 16 KB) = 96 KB
#define CONV_LDS_BYTES (3*32768)

typedef __attribute__((ext_vector_type(8))) short short8;
typedef __attribute__((ext_vector_type(4))) float f32x4;

__device__ __forceinline__ void gload_lds16(const void* g, void* l) {
    __builtin_amdgcn_global_load_lds(
        (const __attribute__((address_space(1))) void*)g,
        (__attribute__((address_space(3))) void*)l, 16, 0, 0);
}

// ---------------------------------------------------------------------------
// x [8][128][64][64] f32  ->  xTp [8][68][68][128] bf16 (2-px zero halo)
__global__ __launch_bounds__(256) void k_xpad(const float* __restrict__ x,
                                              __hip_bfloat16* __restrict__ xTp) {
    int bh = blockIdx.x; int b = bh >> 6, h = bh & 63;
    __shared__ __hip_bfloat16 tile[64][130];
    int t = threadIdx.x;
#pragma unroll
    for (int i = 0; i < 32; ++i) {
        int e = (i << 8) + t; int w = e & 63; int ci = e >> 6;
        tile[w][ci] = __float2bfloat16(x[(((size_t)(b*128 + ci))*64 + h)*64 + w]);
    }
    __syncthreads();
    __hip_bfloat16* dst = xTp + ((size_t)((b*68 + h + 2)*68 + 2))*128;
#pragma unroll
    for (int i = 0; i < 32; ++i) {
        int e = (i << 8) + t; int ci = e & 127; int w = e >> 7;
        dst[w*128 + ci] = tile[w][ci];
    }
}

// ---------------------------------------------------------------------------
// w_mid [128][16][128][3][3] f32 -> wB2 [p][nt(4)][kt(36)][nl(256)][kk(32)]
__global__ void k_wrepack(const float* __restrict__ w_mid,
                          __hip_bfloat16* __restrict__ wB2) {
    int idx = blockIdx.x * 256 + threadIdx.x;
    if (idx >= WB2_ELEMS) return;
    int kk  = idx & 31;
    int nl  = (idx >> 5) & 255;
    int q   = idx >> 13;             // (p*4+nt)*36 + kt
    int kt  = q % 36;
    int pnt = q / 36;                // 0..7
    int nt  = pnt & 3, p = pnt >> 2;
    int c = ((nt*16 + (nl >> 4)) << 1) + p;
    int m = nl & 15;
    int k = kt*32 + kk;
    int tap = k >> 7, ci = k & 127;
    wB2[idx] = __float2bfloat16(w_mid[((size_t)((c*16 + m)*128 + ci))*9 + tap]);
}

// ---------------------------------------------------------------------------
// Implicit-GEMM conv: BM=256 spatial x BN=256 cols, BK=32, 8 waves (2M x 4N),
// per-wave 128x64, acc 8x4 (128 AGPR). 3 rotating LDS buffer sets (96 KB
// dynamic), counted vmcnt(4) distance-2 (R14-proven ledger). NEW: each K-step
// is split into 4 sub-phases {issue 1 gload (step u+2), ds_read one A-quad
// (+ B-frags in sub0), setprio, 8 MFMA, barrier} so every inter-barrier span
// has MFMA covering memory issue (m201 8-phase rationale).
__global__ __launch_bounds__(512, 2) void k_conv(
    const __hip_bfloat16* __restrict__ xTp,
    const __hip_bfloat16* __restrict__ wB2,
    const float* __restrict__ w_pt,
    const float* __restrict__ b_pt,
    float* __restrict__ y) {
    extern __shared__ char smem[];
    __hip_bfloat16* Alds = (__hip_bfloat16*)smem;              // 3 x 8192 elems
    __hip_bfloat16* Blds = (__hip_bfloat16*)(smem + 49152);    // 3 x 8192 elems

    // combo -> XCD: one (p, nt) per XCD; B slice 576 KB L2-resident
    const int combo = blockIdx.x & 7;
    const int p  = combo & 1;
    const int nt = combo >> 1;           // 0..3 (cols nt*256..+255 within parity)
    const int mt = blockIdx.x >> 3;      // spatial tile 0..127 (256 rows each)
    const int dil = 1 + p;

    const int t = threadIdx.x;           // 0..511
    const int lane = t & 63;
    const int wave = t >> 6;             // 0..7
    const int wm = wave >> 2;            // 0..1
    const int wn = wave & 3;             // 0..3
    const int lm = lane & 15, lg = lane >> 4;

    const int rsub = t >> 2;                              // staging row 0..127
    const int ksub = (((t & 3) ^ ((t >> 3) & 3)) << 3);   // src-side swizzled slot

    // A source pointers for row-rounds 0 (rows 0..127) and 1 (rows 128..255)
    const __hip_bfloat16* abase0;
    const __hip_bfloat16* abase1;
    {
        int s0 = mt*256 + rsub;
        int s1 = s0 + 128;
        abase0 = xTp + ((size_t)(((s0>>12)*68 + ((s0>>6)&63) + 2)*68 + (s0&63) + 2))*128 + ksub;
        abase1 = xTp + ((size_t)(((s1>>12)*68 + ((s1>>6)&63) + 2)*68 + (s1&63) + 2))*128 + ksub;
    }
    // B source: [p][nt][kt][nl 256][kk 32]; kt stride 8192 elems; round1 +4096
    const __hip_bfloat16* bbase = wB2 + (size_t)p*(4*36*8192) + (size_t)nt*(36*8192)
                                + rsub*32 + ksub;

#define TOFF(u) (dil*(128*((((u) >> 2)/3 - 1)*68 + (((u) >> 2)%3 - 1))) + ((u) & 3)*32)
    // part q: 0 = A rows 0-127, 1 = A rows 128-255, 2 = B cols 0-127, 3 = B cols 128-255
#define ISSUE_PART(u, bufi, q) do {                                                        \
    if ((q) == 0)      gload_lds16(abase0 + TOFF(u), (char*)Alds + (bufi)*16384 + t*16);   \
    else if ((q) == 1) gload_lds16(abase1 + TOFF(u), (char*)Alds + (bufi)*16384 + 8192 + t*16); \
    else if ((q) == 2) gload_lds16(bbase + (size_t)(u)*8192, (char*)Blds + (bufi)*16384 + t*16); \
    else               gload_lds16(bbase + (size_t)(u)*8192 + 4096, (char*)Blds + (bufi)*16384 + 8192 + t*16); \
  } while (0)

    f32x4 acc[8][4];
#pragma unroll
    for (int i = 0; i < 8; ++i)
#pragma unroll
        for (int j = 0; j < 4; ++j) acc[i][j] = (f32x4){0.f, 0.f, 0.f, 0.f};

    const int sslot = (lg ^ ((lm >> 1) & 3)) << 3;   // read-side swizzled slot
    const int abase_off = (wm*128 + lm)*32 + sslot;  // + i*512 per fragment
    int boff[4];
#pragma unroll
    for (int j = 0; j < 4; ++j)
        boff[j] = (wn*64 + j*16 + lm)*32 + sslot;

    // prologue: issue steps 0 and 1 (4 parts each)
#pragma unroll
    for (int q = 0; q < 4; ++q) ISSUE_PART(0, 0, q);
#pragma unroll
    for (int q = 0; q < 4; ++q) ISSUE_PART(1, 1, q);

#pragma unroll
    for (int u = 0; u < 36; ++u) {
        const int bi  = u % 3;
        const int bi2 = (u + 2) % 3;
        // wait for step u's 4 loads (leave step u+1's 4 in flight); tail: drain
        if (u < 35) asm volatile("s_waitcnt vmcnt(4)" ::: "memory");
        else        asm volatile("s_waitcnt vmcnt(0)" ::: "memory");
        __builtin_amdgcn_s_barrier();          // all waves' step-u data visible
        __builtin_amdgcn_sched_barrier(0);

        short8 bf[4];
#pragma unroll
        for (int sq = 0; sq < 4; ++sq) {
            if (u + 2 < 36) ISSUE_PART(u + 2, bi2, sq);
            if (sq == 0) {
#pragma unroll
                for (int j = 0; j < 4; ++j)
                    bf[j] = *(const short8*)(Blds + bi*8192 + boff[j]);
            }
            short8 a0 = *(const short8*)(Alds + bi*8192 + abase_off + (2*sq)*512);
            short8 a1 = *(const short8*)(Alds + bi*8192 + abase_off + (2*sq+1)*512);
            __builtin_amdgcn_s_setprio(1);
#pragma unroll
            for (int j = 0; j < 4; ++j)
                acc[2*sq][j] = __builtin_amdgcn_mfma_f32_16x16x32_bf16(
                    a0, bf[j], acc[2*sq][j], 0, 0, 0);
#pragma unroll
            for (int j = 0; j < 4; ++j)
                acc[2*sq+1][j] = __builtin_amdgcn_mfma_f32_16x16x32_bf16(
                    a1, bf[j], acc[2*sq+1][j], 0, 0, 0);
            __builtin_amdgcn_s_setprio(0);
            if (sq < 3) __builtin_amdgcn_s_barrier();   // sub-phase alignment
        }
        // quad3's reads precede step u+1's entry barrier -> WAR-safe vs its ISSUEs
    }
#undef ISSUE_PART
#undef TOFF

    // epilogue: leaky -> *w_pt -> reduce over m (16 lanes) -> +b_pt -> y
#pragma unroll
    for (int j = 0; j < 4; ++j) {
        int n_g = nt*256 + wn*64 + j*16 + lm;
        int c = ((n_g >> 4) << 1) + p;     // uniform across the 16-lane group
        float wp = w_pt[c*16 + lm];        // m == lm
        float bp = b_pt[c];
#pragma unroll
        for (int i = 0; i < 8; ++i) {
#pragma unroll
            for (int r = 0; r < 4; ++r) {
                float v = acc[i][j][r];
                v = v >= 0.f ? v : 0.1f*v;
                v *= wp;
                v += __shfl_xor(v, 1);
                v += __shfl_xor(v, 2);
                v += __shfl_xor(v, 4);
                v += __shfl_xor(v, 8);
                if (lm == 0) {
                    int s = mt*256 + wm*128 + i*16 + lg*4 + r;
                    int b = s >> 12, hw = s & 4095;
                    y[(size_t)(b*128 + c)*4096 + hw] = v + bp;
                }
            }
        }
    }
}

// ---------------------------------------------------------------------------
// per-(b,c)-plane partial sums (float4 loads, no atomics, deterministic)
__global__ __launch_bounds__(256) void k_ystat(const float* __restrict__ y,
                                               float2* __restrict__ partials) {
    int P = blockIdx.x;                 // plane = b*128 + c
    const float4* base = (const float4*)(y + (size_t)P*4096);
    int t = threadIdx.x;
    float s = 0.f, s2 = 0.f;
#pragma unroll
    for (int i = 0; i < 4; ++i) {
        float4 v = base[t + i*256];
        s  += v.x + v.y + v.z + v.w;
        s2 += v.x*v.x + v.y*v.y + v.z*v.z + v.w*v.w;
    }
#pragma unroll
    for (int o = 32; o; o >>= 1) { s += __shfl_down(s, o); s2 += __shfl_down(s2, o); }
    __shared__ float ss[4], ss2[4];
    if ((t & 63) == 0) { ss[t >> 6] = s; ss2[t >> 6] = s2; }
    __syncthreads();
    if (t == 0)
        partials[P] = make_float2(ss[0]+ss[1]+ss[2]+ss[3], ss2[0]+ss2[1]+ss2[2]+ss2[3]);
}

// BN finalize + apply + ReLU. Block covers 256 float4 = quarter of one plane.
__global__ __launch_bounds__(256) void k_bn_apply(float* __restrict__ y,
                                                  const float2* __restrict__ partials,
                                                  const float* __restrict__ gamma,
                                                  const float* __restrict__ beta) {
    int bid = blockIdx.x;
    int c = (bid >> 2) & 127;
    float s = 0.f, s2 = 0.f;
#pragma unroll
    for (int b = 0; b < 8; ++b) {
        float2 pr = partials[b*128 + c];
        s += pr.x; s2 += pr.y;
    }
    float mean = s * (1.f/32768.f);
    float var  = s2 * (1.f/32768.f) - mean*mean;
    float scale = gamma[c] * rsqrtf(var + EPSV);
    float shift = beta[c] - mean*scale;
    float4* y4 = (float4*)y;
    int idx = bid*256 + threadIdx.x;
    float4 v = y4[idx];
    v.x = fmaxf(v.x*scale + shift, 0.f);
    v.y = fmaxf(v.y*scale + shift, 0.f);
    v.z = fmaxf(v.z*scale + shift, 0.f);
    v.w = fmaxf(v.w*scale + shift, 0.f);
    y4[idx] = v;
}

// ---------------------------------------------------------------------------
extern "C" void kernel_launch(void* const* d_in, const int* in_sizes, int n_in,
                              void* d_out, int out_size, void* d_ws, size_t ws_size,
                              hipStream_t stream) {
    const float* x     = (const float*)d_in[0];
    const float* w_mid = (const float*)d_in[1];
    const float* w_pt  = (const float*)d_in[2];
    const float* b_pt  = (const float*)d_in[3];
    const float* gamma = (const float*)d_in[4];
    const float* beta  = (const float*)d_in[5];
    float* y = (float*)d_out;

    __hip_bfloat16* wB2 = (__hip_bfloat16*)d_ws;
    __hip_bfloat16* xTp = (__hip_bfloat16*)((char*)d_ws + WB2_BYTES);
    float2* partials    = (float2*)((char*)d_ws + STATS_OFF);

    // opt in to >64 KB dynamic LDS for k_conv (host-side, graph-capture-safe)
    (void)hipFuncSetAttribute((const void*)k_conv,
                              hipFuncAttributeMaxDynamicSharedMemorySize,
                              CONV_LDS_BYTES);

    hipMemsetAsync(xTp, 0, XTP_BYTES, stream);                  // zero halo
    k_xpad<<<512, 256, 0, stream>>>(x, xTp);
    k_wrepack<<<(WB2_ELEMS + 255) / 256, 256, 0, stream>>>(w_mid, wB2);
    k_conv<<<1024, 512, CONV_LDS_BYTES, stream>>>(xTp, wB2, w_pt, b_pt, y);
    k_ystat<<<1024, 256, 0, stream>>>(y, partials);
    k_bn_apply<<<4096, 256, 0, stream>>>(y, partials, gamma, beta);
}